// Round 8
// baseline (1424.847 us; speedup 1.0000x reference)
//
#include <hip/hip_runtime.h>
#include <hip/hip_bf16.h>

// Problem constants (RWKV-7 Tmix: B=2, T=1024, C=2048, H=32, N=64)
#define BB 2
#define TT 1024
#define CC 2048
#define HH 32
#define BT 2048          // BB*TT tokens
#define GN_EPS 6.4e-4f   // 1e-5 * 8^2

typedef __attribute__((ext_vector_type(8))) __bf16 bf16x8;
typedef __attribute__((ext_vector_type(4))) float f32x4;

__device__ __forceinline__ float sigf(float x) { return 1.0f / (1.0f + expf(-x)); }

__device__ __forceinline__ void split_bf16(float x, __hip_bfloat16& hi, __hip_bfloat16& lo) {
  __hip_bfloat16 h = __float2bfloat16(x);
  hi = h;
  lo = __float2bfloat16(x - __bfloat162float(h));
}

// Sum over each aligned 16-lane group, pure DPP (no LDS pipe on the chain).
__device__ __forceinline__ float red16(float x) {
  x += __int_as_float(__builtin_amdgcn_update_dpp(
      0, __float_as_int(x), 0xB1 /*quad_perm [1,0,3,2]*/, 0xF, 0xF, true));
  x += __int_as_float(__builtin_amdgcn_update_dpp(
      0, __float_as_int(x), 0x4E /*quad_perm [2,3,0,1]*/, 0xF, 0xF, true));
  x += __int_as_float(__builtin_amdgcn_update_dpp(
      0, __float_as_int(x), 0x141 /*row_half_mirror*/, 0xF, 0xF, true));
  x += __int_as_float(__builtin_amdgcn_update_dpp(
      0, __float_as_int(x), 0x140 /*row_mirror*/, 0xF, 0xF, true));
  return x;
}

// ---------------------------------------------------------------------------
// K1: token shift + six lerped projections. r/k/v hi+lo split; w/a/g bf16.
// ---------------------------------------------------------------------------
__global__ __launch_bounds__(256) void k_prepx(
    const float* __restrict__ hid, const float* __restrict__ shift,
    const float* __restrict__ xrc, const float* __restrict__ xwc,
    const float* __restrict__ xkc, const float* __restrict__ xvc,
    const float* __restrict__ xac, const float* __restrict__ xgc,
    __hip_bfloat16* __restrict__ xrh, __hip_bfloat16* __restrict__ xrl,
    __hip_bfloat16* __restrict__ xw,
    __hip_bfloat16* __restrict__ xkh, __hip_bfloat16* __restrict__ xkl,
    __hip_bfloat16* __restrict__ xvh, __hip_bfloat16* __restrict__ xvl,
    __hip_bfloat16* __restrict__ xa, __hip_bfloat16* __restrict__ xg) {
  int idx = blockIdx.x * 256 + threadIdx.x;   // < BT*CC
  int c  = idx & (CC - 1);
  int bt = idx >> 11;
  int t  = bt & (TT - 1);
  int b  = bt >> 10;
  float hcur  = hid[idx];
  float hprev = (t == 0) ? shift[b * CC + c] : hid[idx - CC];
  float xx = hprev - hcur;
  split_bf16(fmaf(xx, xrc[c], hcur), xrh[idx], xrl[idx]);
  split_bf16(fmaf(xx, xkc[c], hcur), xkh[idx], xkl[idx]);
  split_bf16(fmaf(xx, xvc[c], hcur), xvh[idx], xvl[idx]);
  xw[idx] = __float2bfloat16(fmaf(xx, xwc[c], hcur));
  xa[idx] = __float2bfloat16(fmaf(xx, xac[c], hcur));
  xg[idx] = __float2bfloat16(fmaf(xx, xgc[c], hcur));
}

// ---------------------------------------------------------------------------
// K2: f32 -> hi+lo bf16 split (for Wr/Wk/Wv/Wo)
// ---------------------------------------------------------------------------
__global__ __launch_bounds__(256) void k_cvt2(const float* __restrict__ in,
                                              __hip_bfloat16* __restrict__ oh,
                                              __hip_bfloat16* __restrict__ ol) {
  int i = blockIdx.x * 256 + threadIdx.x;
  split_bf16(in[i], oh[i], ol[i]);
}

// ---------------------------------------------------------------------------
// K3: transpose-convert small LoRA "up" weights: in [2048][N0] f32 ->
//     out [NP][2048] bf16 (rows >= N0 zero-padded).  (stage-1 B operands)
// ---------------------------------------------------------------------------
__global__ __launch_bounds__(256) void k_tr(const float* __restrict__ in,
                                            __hip_bfloat16* __restrict__ out,
                                            int N0) {
  int i = blockIdx.x * 256 + threadIdx.x;   // over NP*2048, grid exact
  int n = i >> 11;
  int k = i & 2047;
  float v = (n < N0) ? in[k * N0 + n] : 0.0f;
  out[i] = __float2bfloat16(v);
}

// ---------------------------------------------------------------------------
// K3b: transpose + hi/lo split of stage-2 "down" weights:
//   in [N0][CC] f32 -> out [CC][K0] bf16 hi+lo (K0 = 1<<lgK, rows>=N0 zero).
// ---------------------------------------------------------------------------
__global__ __launch_bounds__(256) void k_trs(const float* __restrict__ in,
                                             __hip_bfloat16* __restrict__ oh,
                                             __hip_bfloat16* __restrict__ ol,
                                             int N0, int lgK) {
  int i = blockIdx.x * 256 + threadIdx.x;   // over CC*K0, grid exact
  int n = i >> lgK;
  int k = i & ((1 << lgK) - 1);
  float v = (k < N0) ? in[k * CC + n] : 0.0f;
  split_bf16(v, oh[i], ol[i]);
}

// ---------------------------------------------------------------------------
// K4: plain bf16 MFMA GEMM, C[M,N] f32 = A[M,K] @ B[N,K]^T  (stage-1 LoRA)
// ROUND-15: __launch_bounds__(256,2) (VGPR cap 256, was 64 — couldn't hold
// even one k-iteration's 6 operands + 32 acc in flight) + explicit 2-stage
// software pipeline (X/Y operand double-buffer).
// ---------------------------------------------------------------------------
__global__ __launch_bounds__(256, 2) void k_gemm_bt(
    const __hip_bfloat16* __restrict__ A, const __hip_bfloat16* __restrict__ Bm,
    float* __restrict__ Cm, int M, int Nn, int K) {
  int tid  = threadIdx.x;
  int lane = tid & 63;
  int wv   = tid >> 6;
  int l15  = lane & 15;
  int quad = lane >> 4;
  int m0 = blockIdx.x * 128 + wv * 32;
  int n0 = blockIdx.y * 64;
  const __hip_bfloat16* ap0 = A + (size_t)(m0 + l15) * K + quad * 8;
  const __hip_bfloat16* ap1 = ap0 + (size_t)16 * K;
  const __hip_bfloat16* bp  = Bm + (size_t)(n0 + l15) * K + quad * 8;
  f32x4 z = {0.f, 0.f, 0.f, 0.f};
  f32x4 c00 = z, c01 = z, c02 = z, c03 = z;
  f32x4 c10 = z, c11 = z, c12 = z, c13 = z;

#define LD6(P, KO)                                                           \
  P##a0 = *(const bf16x8*)(ap0 + (KO));                                      \
  P##a1 = *(const bf16x8*)(ap1 + (KO));                                      \
  P##b0 = *(const bf16x8*)(bp + (KO));                                       \
  P##b1 = *(const bf16x8*)(bp + (size_t)16 * K + (KO));                      \
  P##b2 = *(const bf16x8*)(bp + (size_t)32 * K + (KO));                      \
  P##b3 = *(const bf16x8*)(bp + (size_t)48 * K + (KO));
#define MM8(P)                                                               \
  c00 = __builtin_amdgcn_mfma_f32_16x16x32_bf16(P##a0, P##b0, c00, 0, 0, 0); \
  c01 = __builtin_amdgcn_mfma_f32_16x16x32_bf16(P##a0, P##b1, c01, 0, 0, 0); \
  c02 = __builtin_amdgcn_mfma_f32_16x16x32_bf16(P##a0, P##b2, c02, 0, 0, 0); \
  c03 = __builtin_amdgcn_mfma_f32_16x16x32_bf16(P##a0, P##b3, c03, 0, 0, 0); \
  c10 = __builtin_amdgcn_mfma_f32_16x16x32_bf16(P##a1, P##b0, c10, 0, 0, 0); \
  c11 = __builtin_amdgcn_mfma_f32_16x16x32_bf16(P##a1, P##b1, c11, 0, 0, 0); \
  c12 = __builtin_amdgcn_mfma_f32_16x16x32_bf16(P##a1, P##b2, c12, 0, 0, 0); \
  c13 = __builtin_amdgcn_mfma_f32_16x16x32_bf16(P##a1, P##b3, c13, 0, 0, 0);

  bf16x8 Xa0, Xa1, Xb0, Xb1, Xb2, Xb3;
  bf16x8 Ya0, Ya1, Yb0, Yb1, Yb2, Yb3;
  LD6(X, 0)
  for (int k0 = 0; k0 < K; k0 += 64) {
    LD6(Y, k0 + 32)
    MM8(X)
    if (k0 + 64 < K) { LD6(X, k0 + 64) }
    MM8(Y)
  }
#undef LD6
#undef MM8
  int colb = n0 + l15;
  int row0 = m0 + quad * 4;
#pragma unroll
  for (int r = 0; r < 4; ++r) {
    Cm[(row0 + r) * Nn + colb +  0] = c00[r];
    Cm[(row0 + r) * Nn + colb + 16] = c01[r];
    Cm[(row0 + r) * Nn + colb + 32] = c02[r];
    Cm[(row0 + r) * Nn + colb + 48] = c03[r];
    Cm[(row0 + 16 + r) * Nn + colb +  0] = c10[r];
    Cm[(row0 + 16 + r) * Nn + colb + 16] = c11[r];
    Cm[(row0 + 16 + r) * Nn + colb + 32] = c12[r];
    Cm[(row0 + 16 + r) * Nn + colb + 48] = c13[r];
  }
}

// ---------------------------------------------------------------------------
// K4b: split-precision GEMM: C = (Ah+Al)@(Bh+Bl)^T ~= Ah Bh + Ah Bl + Al Bh.
// ROUND-15: VGPR_Count was 64 — one k-iteration needs 48 operand + 32 acc
// VGPRs, so every load->MFMA was serialized at L2 latency (MfmaUtil 11%).
// Fix: __launch_bounds__(256,2) (cap 256) + X/Y double-buffered k-loop:
// loads for chunk n+1 fly under the 24 MFMAs of chunk n. K multiple of 64.
// ---------------------------------------------------------------------------
__global__ __launch_bounds__(256, 2) void k_gemm_bt3(
    const __hip_bfloat16* __restrict__ Ah, const __hip_bfloat16* __restrict__ Al,
    const __hip_bfloat16* __restrict__ Bh, const __hip_bfloat16* __restrict__ Bl,
    float* __restrict__ Cm, int M, int Nn, int K) {
  int tid  = threadIdx.x;
  int lane = tid & 63;
  int wv   = tid >> 6;
  int l15  = lane & 15;
  int quad = lane >> 4;
  int m0 = blockIdx.x * 128 + wv * 32;
  int n0 = blockIdx.y * 64;
  size_t aoff0 = (size_t)(m0 + l15) * K + quad * 8;
  size_t aoff1 = aoff0 + (size_t)16 * K;
  size_t boff  = (size_t)(n0 + l15) * K + quad * 8;
  f32x4 z = {0.f, 0.f, 0.f, 0.f};
  f32x4 c00 = z, c01 = z, c02 = z, c03 = z;
  f32x4 c10 = z, c11 = z, c12 = z, c13 = z;

#define LD12(P, KO)                                                          \
  P##a0h = *(const bf16x8*)(Ah + aoff0 + (KO));                              \
  P##a1h = *(const bf16x8*)(Ah + aoff1 + (KO));                              \
  P##a0l = *(const bf16x8*)(Al + aoff0 + (KO));                              \
  P##a1l = *(const bf16x8*)(Al + aoff1 + (KO));                              \
  P##bh0 = *(const bf16x8*)(Bh + boff + (KO));                               \
  P##bh1 = *(const bf16x8*)(Bh + boff + (size_t)16 * K + (KO));              \
  P##bh2 = *(const bf16x8*)(Bh + boff + (size_t)32 * K + (KO));              \
  P##bh3 = *(const bf16x8*)(Bh + boff + (size_t)48 * K + (KO));              \
  P##bl0 = *(const bf16x8*)(Bl + boff + (KO));                               \
  P##bl1 = *(const bf16x8*)(Bl + boff + (size_t)16 * K + (KO));              \
  P##bl2 = *(const bf16x8*)(Bl + boff + (size_t)32 * K + (KO));              \
  P##bl3 = *(const bf16x8*)(Bl + boff + (size_t)48 * K + (KO));
#define MM24(P)                                                              \
  c00 = __builtin_amdgcn_mfma_f32_16x16x32_bf16(P##a0h, P##bh0, c00, 0, 0, 0); \
  c01 = __builtin_amdgcn_mfma_f32_16x16x32_bf16(P##a0h, P##bh1, c01, 0, 0, 0); \
  c02 = __builtin_amdgcn_mfma_f32_16x16x32_bf16(P##a0h, P##bh2, c02, 0, 0, 0); \
  c03 = __builtin_amdgcn_mfma_f32_16x16x32_bf16(P##a0h, P##bh3, c03, 0, 0, 0); \
  c10 = __builtin_amdgcn_mfma_f32_16x16x32_bf16(P##a1h, P##bh0, c10, 0, 0, 0); \
  c11 = __builtin_amdgcn_mfma_f32_16x16x32_bf16(P##a1h, P##bh1, c11, 0, 0, 0); \
  c12 = __builtin_amdgcn_mfma_f32_16x16x32_bf16(P##a1h, P##bh2, c12, 0, 0, 0); \
  c13 = __builtin_amdgcn_mfma_f32_16x16x32_bf16(P##a1h, P##bh3, c13, 0, 0, 0); \
  c00 = __builtin_amdgcn_mfma_f32_16x16x32_bf16(P##a0h, P##bl0, c00, 0, 0, 0); \
  c01 = __builtin_amdgcn_mfma_f32_16x16x32_bf16(P##a0h, P##bl1, c01, 0, 0, 0); \
  c02 = __builtin_amdgcn_mfma_f32_16x16x32_bf16(P##a0h, P##bl2, c02, 0, 0, 0); \
  c03 = __builtin_amdgcn_mfma_f32_16x16x32_bf16(P##a0h, P##bl3, c03, 0, 0, 0); \
  c10 = __builtin_amdgcn_mfma_f32_16x16x32_bf16(P##a1h, P##bl0, c10, 0, 0, 0); \
  c11 = __builtin_amdgcn_mfma_f32_16x16x32_bf16(P##a1h, P##bl1, c11, 0, 0, 0); \
  c12 = __builtin_amdgcn_mfma_f32_16x16x32_bf16(P##a1h, P##bl2, c12, 0, 0, 0); \
  c13 = __builtin_amdgcn_mfma_f32_16x16x32_bf16(P##a1h, P##bl3, c13, 0, 0, 0); \
  c00 = __builtin_amdgcn_mfma_f32_16x16x32_bf16(P##a0l, P##bh0, c00, 0, 0, 0); \
  c01 = __builtin_amdgcn_mfma_f32_16x16x32_bf16(P##a0l, P##bh1, c01, 0, 0, 0); \
  c02 = __builtin_amdgcn_mfma_f32_16x16x32_bf16(P##a0l, P##bh2, c02, 0, 0, 0); \
  c03 = __builtin_amdgcn_mfma_f32_16x16x32_bf16(P##a0l, P##bh3, c03, 0, 0, 0); \
  c10 = __builtin_amdgcn_mfma_f32_16x16x32_bf16(P##a1l, P##bh0, c10, 0, 0, 0); \
  c11 = __builtin_amdgcn_mfma_f32_16x16x32_bf16(P##a1l, P##bh1, c11, 0, 0, 0); \
  c12 = __builtin_amdgcn_mfma_f32_16x16x32_bf16(P##a1l, P##bh2, c12, 0, 0, 0); \
  c13 = __builtin_amdgcn_mfma_f32_16x16x32_bf16(P##a1l, P##bh3, c13, 0, 0, 0);

  bf16x8 Xa0h, Xa1h, Xa0l, Xa1l, Xbh0, Xbh1, Xbh2, Xbh3, Xbl0, Xbl1, Xbl2, Xbl3;
  bf16x8 Ya0h, Ya1h, Ya0l, Ya1l, Ybh0, Ybh1, Ybh2, Ybh3, Ybl0, Ybl1, Ybl2, Ybl3;
  LD12(X, 0)
  for (int k0 = 0; k0 < K; k0 += 64) {
    LD12(Y, k0 + 32)
    MM24(X)
    if (k0 + 64 < K) { LD12(X, k0 + 64) }
    MM24(Y)
  }
#undef LD12
#undef MM24
  int colb = n0 + l15;
  int row0 = m0 + quad * 4;
#pragma unroll
  for (int r = 0; r < 4; ++r) {
    Cm[(row0 + r) * Nn + colb +  0] = c00[r];
    Cm[(row0 + r) * Nn + colb + 16] = c01[r];
    Cm[(row0 + r) * Nn + colb + 32] = c02[r];
    Cm[(row0 + r) * Nn + colb + 48] = c03[r];
    Cm[(row0 + 16 + r) * Nn + colb +  0] = c10[r];
    Cm[(row0 + 16 + r) * Nn + colb + 16] = c11[r];
    Cm[(row0 + 16 + r) * Nn + colb + 32] = c12[r];
    Cm[(row0 + 16 + r) * Nn + colb + 48] = c13[r];
  }
}

// ---------------------------------------------------------------------------
// K5: activations + hi/lo split of stage-1 LoRA outputs (MFMA stage-2 prep).
// ---------------------------------------------------------------------------
__global__ __launch_bounds__(256) void k_act2(
    const float* __restrict__ h1w, const float* __restrict__ h1a,
    const float* __restrict__ h1v, const float* __restrict__ h1g,
    __hip_bfloat16* __restrict__ wh, __hip_bfloat16* __restrict__ wl,
    __hip_bfloat16* __restrict__ ah, __hip_bfloat16* __restrict__ al,
    __hip_bfloat16* __restrict__ vh, __hip_bfloat16* __restrict__ vl,
    __hip_bfloat16* __restrict__ gh, __hip_bfloat16* __restrict__ gl) {
  int i = blockIdx.x * 256 + threadIdx.x;   // grid covers BT*128 exactly
  if (i < BT * 64) {
    split_bf16(tanhf(h1w[i]), wh[i], wl[i]);
    split_bf16(h1a[i], ah[i], al[i]);
    split_bf16(h1v[i], vh[i], vl[i]);
  }
  split_bf16(sigf(h1g[i]), gh[i], gl[i]);
}

// ---------------------------------------------------------------------------
// K6: elementwise gates + kk-normalize + per-head bonus. wave == head.
// ---------------------------------------------------------------------------
__global__ __launch_bounds__(256) void k_gate(
    const float* __restrict__ h2w, const float* __restrict__ h2a,
    const float* __restrict__ h2v,
    const float* __restrict__ w0, const float* __restrict__ a0,
    const float* __restrict__ v0, const float* __restrict__ kkc,
    const float* __restrict__ kac, float* __restrict__ kbuf,
    float* __restrict__ vbuf, const float* __restrict__ vfirst,
    const float* __restrict__ rbuf, const float* __restrict__ rk,
    float* __restrict__ dec, float* __restrict__ aw,
    float* __restrict__ bw, float* __restrict__ bonb) {
  int idx = blockIdx.x * 256 + threadIdx.x;   // < BT*CC
  int c = idx & (CC - 1);
  float kv = kbuf[idx], vv = vbuf[idx], vf = vfirst[idx];
  float d_ = 0.60653065971f * sigf(w0[c] + h2w[idx]);   // sigmoid * e^-0.5
  float as = sigf(a0[c] + h2a[idx]);
  float vs = sigf(v0[c] + h2v[idx]);
  float vm = vv + (vf - vv) * vs;
  float kfv = kv * (1.0f + kac[c] * (as - 1.0f));
  float kku = kv * kkc[c];
  float s = kku * kku;     // per-head L2 over 64 lanes (wave == head)
  s += __shfl_xor(s, 1);  s += __shfl_xor(s, 2);  s += __shfl_xor(s, 4);
  s += __shfl_xor(s, 8);  s += __shfl_xor(s, 16); s += __shfl_xor(s, 32);
  float nrm = fmaxf(sqrtf(s), 1e-12f);
  float kkn = kku / nrm;
  float bon = rbuf[idx] * kfv * rk[c];
  bon += __shfl_xor(bon, 1);  bon += __shfl_xor(bon, 2);
  bon += __shfl_xor(bon, 4);  bon += __shfl_xor(bon, 8);
  bon += __shfl_xor(bon, 16); bon += __shfl_xor(bon, 32);
  if ((threadIdx.x & 63) == 0) bonb[(idx >> 11) * HH + (c >> 6)] = bon;
  dec[idx] = d_;
  aw[idx]  = -kkn; bw[idx] = kkn * as;
  kbuf[idx] = kfv; vbuf[idx] = vm;
}

// ---------------------------------------------------------------------------
// K7: WKV7 scan — round-14 LDS-DMA-ring version (passing, 185 µs), unchanged.
// ---------------------------------------------------------------------------
__global__ __launch_bounds__(64, 1) void k_scan(
    const float* __restrict__ rbuf, const float* __restrict__ kf,
    const float* __restrict__ dec, const float* __restrict__ aw,
    const float* __restrict__ bw, const float* __restrict__ vbuf,
    const float* __restrict__ st0, float* __restrict__ ybuf) {
  __shared__ __align__(16) char ldsbuf[16 * 2048];
  int blk = blockIdx.x;                     // 0..1023
  int xcd = blk & 7;
  int q   = blk >> 3;                       // 0..127
  int bh  = xcd * 8 + (q & 7);              // 16 rg-waves of a head share blk%8
  int rg  = q >> 3;                         // 0..15
  int b = bh >> 5, h = bh & 31;
  int lane = threadIdx.x;
  int l15  = lane & 15;
  int row  = rg * 4 + (lane >> 4);
  size_t tokbase = (size_t)b * TT * CC + h * 64;

  f32x4 S = *(const f32x4*)(st0 + ((size_t)bh * 64 + row) * 64 + l15 * 4);
  bool writer = (l15 == 0);
  float* yout = ybuf + tokbase + row;

  // per-lane DMA source pointers (advance +CC per token, all lanes uniform)
  const float* g1 = (lane < 16 ? rbuf : lane < 32 ? kf : lane < 48 ? dec : aw)
                  + tokbase + l15 * 4;
  const float* g2 = (lane < 16) ? (bw + tokbase + l15 * 4)
                                : (vbuf + tokbase + rg * 4);  // lanes>=16: v rows (16 real, rest pad)

  // LDS byte offsets (relative to workgroup LDS base)
  unsigned lbase = (unsigned)(uintptr_t)(__attribute__((address_space(3))) char*)ldsbuf;
  unsigned larr = lbase + (unsigned)(l15 * 16);          // +slot: arrays at 0/256/512/768/1024
  unsigned lvad = lbase + 1280u + (unsigned)((lane >> 4) * 4);  // +slot: v word

#define DMAQ(T)                                                              \
  { char* sb_ = ldsbuf + (((T) & 15) << 11);                                 \
    __builtin_amdgcn_global_load_lds(                                        \
        (const __attribute__((address_space(1))) void*)g1,                   \
        (__attribute__((address_space(3))) void*)sb_, 16, 0, 0);             \
    __builtin_amdgcn_global_load_lds(                                        \
        (const __attribute__((address_space(1))) void*)g2,                   \
        (__attribute__((address_space(3))) void*)(sb_ + 1024), 16, 0, 0);    \
    g1 += CC; g2 += CC; }

#define DSRD(RR, RK, RD, RA, RB, RV, T)                                      \
  { unsigned a_ = larr + (unsigned)(((T) & 15) << 11);                       \
    unsigned v_ = lvad + (unsigned)(((T) & 15) << 11);                       \
    asm volatile("ds_read_b128 %0, %1"             : "=v"(RR) : "v"(a_));    \
    asm volatile("ds_read_b128 %0, %1 offset:256"  : "=v"(RK) : "v"(a_));    \
    asm volatile("ds_read_b128 %0, %1 offset:512"  : "=v"(RD) : "v"(a_));    \
    asm volatile("ds_read_b128 %0, %1 offset:768"  : "=v"(RA) : "v"(a_));    \
    asm volatile("ds_read_b128 %0, %1 offset:1024" : "=v"(RB) : "v"(a_));    \
    asm volatile("ds_read_b32 %0, %1"              : "=v"(RV) : "v"(v_)); }

#define WVM(N) { asm volatile("s_waitcnt vmcnt(" #N ")" ::: "memory");       \
                 __builtin_amdgcn_sched_barrier(0); }
#define WLG    { asm volatile("s_waitcnt lgkmcnt(0)" ::: "memory");          \
                 __builtin_amdgcn_sched_barrier(0); }

#define STEPR(RR, RK, RD, RA, RB, RV, T)                                     \
  { float sa = fmaf(S.w, RA.w, fmaf(S.z, RA.z,                               \
               fmaf(S.y, RA.y, S.x * RA.x)));                                \
    sa = red16(sa);                                                          \
    float vv = RV;                                                           \
    S.x = fmaf(S.x, RD.x, fmaf(sa, RB.x, vv * RK.x));                        \
    S.y = fmaf(S.y, RD.y, fmaf(sa, RB.y, vv * RK.y));                        \
    S.z = fmaf(S.z, RD.z, fmaf(sa, RB.z, vv * RK.z));                        \
    S.w = fmaf(S.w, RD.w, fmaf(sa, RB.w, vv * RK.w));                        \
    float y = fmaf(S.w, RR.w, fmaf(S.z, RR.z,                                \
              fmaf(S.y, RR.y, S.x * RR.x)));                                 \
    y = red16(y);                                                            \
    if (writer) yout[(size_t)(T) * CC] = y; }

  // prologue: DMA tokens 0..15 (32 vmem ops in flight)
  for (int tt = 0; tt < 16; ++tt) DMAQ(tt)

  f32x4 Ar, Ak, Ad, Aa, Ab; float Av;
  f32x4 Br, Bk, Bd, Ba, Bb; float Bv;

  WVM(24)                      // token 0 landed (30 ops after it; 6 slack)
  DSRD(Ar, Ak, Ad, Aa, Ab, Av, 0)
  WLG

  int t = 0;
  // warm-up pairs: t = 0..15 (prologue-issued tokens; exact budget 30+t)
  for (; t < 16; t += 2) {
    DMAQ(t + 16)
    WVM(24)
    DSRD(Br, Bk, Bd, Ba, Bb, Bv, t + 1)
    STEPR(Ar, Ak, Ad, Aa, Ab, Av, t)
    WLG
    DMAQ(t + 17)
    WVM(24)
    DSRD(Ar, Ak, Ad, Aa, Ab, Av, t + 2)
    STEPR(Br, Bk, Bd, Ba, Bb, Bv, t + 1)
    WLG
  }
  // steady pairs: t = 16..1006 (budget 45; 5 slack)
  for (; t < TT - 16; t += 2) {
    DMAQ(t + 16)
    WVM(40)
    DSRD(Br, Bk, Bd, Ba, Bb, Bv, t + 1)
    STEPR(Ar, Ak, Ad, Aa, Ab, Av, t)
    WLG
    DMAQ(t + 17)
    WVM(40)
    DSRD(Ar, Ak, Ad, Aa, Ab, Av, t + 2)
    STEPR(Br, Bk, Bd, Ba, Bb, Bv, t + 1)
    WLG
  }
  // drain, then waitless tail: t = 1008..1023 (all data resident in LDS)
  asm volatile("s_waitcnt vmcnt(0)" ::: "memory");
  __builtin_amdgcn_sched_barrier(0);
  for (; t < TT; t += 2) {
    DSRD(Br, Bk, Bd, Ba, Bb, Bv, t + 1)
    STEPR(Ar, Ak, Ad, Aa, Ab, Av, t)
    WLG
    if (t + 2 < TT) DSRD(Ar, Ak, Ad, Aa, Ab, Av, t + 2)
    STEPR(Br, Bk, Bd, Ba, Bb, Bv, t + 1)
    WLG
  }
#undef DMAQ
#undef DSRD
#undef WVM
#undef WLG
#undef STEPR
}

// ---------------------------------------------------------------------------
// K8: post-scan epilogue: GroupNorm + bonus + g-gate, fully parallel.
// ---------------------------------------------------------------------------
__global__ __launch_bounds__(256) void k_post(
    const float* __restrict__ ybuf, const float* __restrict__ vb,
    const float* __restrict__ gvb, const float* __restrict__ bonb,
    const float* __restrict__ gnw, const float* __restrict__ gnb,
    __hip_bfloat16* __restrict__ xoh, __hip_bfloat16* __restrict__ xol) {
  int tid = threadIdx.x, wv = tid >> 6, lane = tid & 63;
  int id = blockIdx.x * 4 + wv;        // 0..BT*HH-1
  int bt = id >> 5, h = id & 31;
  size_t base = (size_t)bt * CC + h * 64 + lane;
  float y = ybuf[base];
  float s1 = y, s2 = y * y;
#pragma unroll
  for (int off = 1; off < 64; off <<= 1) {
    s1 += __shfl_xor(s1, off);
    s2 += __shfl_xor(s2, off);
  }
  float mean = s1 * (1.0f / 64.0f);
  float var  = s2 * (1.0f / 64.0f) - mean * mean;
  float inv  = rsqrtf(var + GN_EPS);
  float x = fmaf((y - mean) * inv, gnw[h * 64 + lane], gnb[h * 64 + lane])
          + bonb[bt * HH + h] * vb[base];
  split_bf16(x * gvb[base], xoh[base], xol[base]);
}

// ---------------------------------------------------------------------------
extern "C" void kernel_launch(void* const* d_in, const int* in_sizes, int n_in,
                              void* d_out, int out_size, void* d_ws, size_t ws_size,
                              hipStream_t stream) {
  (void)in_sizes; (void)n_in; (void)out_size; (void)ws_size;
  const float* hid    = (const float*)d_in[0];
  const float* shift  = (const float*)d_in[1];
  const float* st0    = (const float*)d_in[2];
  const float* vfirst = (const float*)d_in[3];
  const float* xrc = (const float*)d_in[4];
  const float* xwc = (const float*)d_in[5];
  const float* xkc = (const float*)d_in[6];
  const float* xvc = (const float*)d_in[7];
  const float* xac = (const float*)d_in[8];
  const float* xgc = (const float*)d_in[9];
  const float* w0  = (const float*)d_in[10];
  const float* w1  = (const float*)d_in[11];
  const float* w2  = (const float*)d_in[12];
  const float* a0  = (const float*)d_in[13];
  const float* a1  = (const float*)d_in[14];
  const float* a2  = (const float*)d_in[15];
  const float* v0  = (const float*)d_in[16];
  const float* v1  = (const float*)d_in[17];
  const float* v2  = (const float*)d_in[18];
  const float* g1  = (const float*)d_in[19];
  const float* g2  = (const float*)d_in[20];
  const float* kkc = (const float*)d_in[21];
  const float* kac = (const float*)d_in[22];
  const float* rk  = (const float*)d_in[23];
  const float* Wr  = (const float*)d_in[24];
  const float* Wk  = (const float*)d_in[25];
  const float* Wv  = (const float*)d_in[26];
  const float* Wo  = (const float*)d_in[27];
  const float* gnw = (const float*)d_in[28];
  const float* gnb = (const float*)d_in[29];
  float* out = (float*)d_out;

  char* p = (char*)d_ws;
  auto alloc = [&](size_t n) { char* q = p; p += (n + 255) & ~(size_t)255; return q; };
  const size_t EL = (size_t)BT * CC;

  // --- alias pool: xrh..xvl + Wrh,Wrl dead by k_gate time; db/awb/bwb +
  //     h2g (the old gvb slot) overlay them.
  char* pool = p;
  __hip_bfloat16* xrh = (__hip_bfloat16*)alloc(EL * 2);
  __hip_bfloat16* xrl = (__hip_bfloat16*)alloc(EL * 2);
  __hip_bfloat16* xkh = (__hip_bfloat16*)alloc(EL * 2);
  __hip_bfloat16* xkl = (__hip_bfloat16*)alloc(EL * 2);
  __hip_bfloat16* xvh = (__hip_bfloat16*)alloc(EL * 2);
  __hip_bfloat16* xvl = (__hip_bfloat16*)alloc(EL * 2);
  __hip_bfloat16* Wrh = (__hip_bfloat16*)alloc((size_t)CC * CC * 2);
  __hip_bfloat16* Wrl = (__hip_bfloat16*)alloc((size_t)CC * CC * 2);
  float* db  = (float*)pool;           // overlays xrh+xrl
  float* awb = db + EL;                // overlays xkh+xkl
  float* bwb = db + 2 * EL;            // overlays xvh+xvl
  float* h2g = db + 3 * EL;            // overlays Wrh+Wrl (old gvb slot)

  __hip_bfloat16* Wkh = (__hip_bfloat16*)alloc((size_t)CC * CC * 2);
  __hip_bfloat16* Wkl = (__hip_bfloat16*)alloc((size_t)CC * CC * 2);
  float* ybuf = (float*)Wkh;           // overlays Wkh+Wkl (dead after k-GEMM)
  float* h2v  = (float*)Wkh;           // same region, read by k_gate BEFORE scan writes ybuf

  __hip_bfloat16* Wvh = (__hip_bfloat16*)alloc((size_t)CC * CC * 2);
  __hip_bfloat16* Wvl = (__hip_bfloat16*)alloc((size_t)CC * CC * 2);
  __hip_bfloat16* Woh = (__hip_bfloat16*)alloc((size_t)CC * CC * 2);
  __hip_bfloat16* Wol = (__hip_bfloat16*)alloc((size_t)CC * CC * 2);
  __hip_bfloat16* xw  = (__hip_bfloat16*)alloc(EL * 2);
  __hip_bfloat16* xa  = (__hip_bfloat16*)alloc(EL * 2);
  __hip_bfloat16* xg  = (__hip_bfloat16*)alloc(EL * 2);
  float* h2w = (float*)xw;             // overlays xw+xa (dead after stage-1 GEMMs)
  __hip_bfloat16* w1t = (__hip_bfloat16*)alloc((size_t)64  * CC * 2);
  __hip_bfloat16* a1t = (__hip_bfloat16*)alloc((size_t)64  * CC * 2);
  __hip_bfloat16* v1t = (__hip_bfloat16*)alloc((size_t)64  * CC * 2);
  __hip_bfloat16* g1t = (__hip_bfloat16*)alloc((size_t)128 * CC * 2);
  float* rb  = (float*)alloc(EL * 4);
  float* kb  = (float*)alloc(EL * 4);  // raw k, then k_final in place
  float* vb  = (float*)alloc(EL * 4);  // raw v, then v_mix in place
  float* h1w = (float*)alloc((size_t)BT * 64  * 4);
  float* h1a = (float*)alloc((size_t)BT * 64  * 4);
  float* h1v = (float*)alloc((size_t)BT * 64  * 4);
  float* h1g = (float*)alloc((size_t)BT * 128 * 4);
  __hip_bfloat16* xoh = (__hip_bfloat16*)alloc(EL * 2);
  __hip_bfloat16* xol = (__hip_bfloat16*)alloc(EL * 2);
  float* h2a = (float*)xoh;            // overlays xoh+xol (k_post writes them AFTER k_gate)
  float* bonb = (float*)alloc((size_t)BT * HH * 4);   // per-(token,head) bonus
  // stage-2 split operands (small, fresh):
  __hip_bfloat16* h1wh = (__hip_bfloat16*)alloc((size_t)BT * 64 * 2);
  __hip_bfloat16* h1wl = (__hip_bfloat16*)alloc((size_t)BT * 64 * 2);
  __hip_bfloat16* h1ah = (__hip_bfloat16*)alloc((size_t)BT * 64 * 2);
  __hip_bfloat16* h1al = (__hip_bfloat16*)alloc((size_t)BT * 64 * 2);
  __hip_bfloat16* h1vh = (__hip_bfloat16*)alloc((size_t)BT * 64 * 2);
  __hip_bfloat16* h1vl = (__hip_bfloat16*)alloc((size_t)BT * 64 * 2);
  __hip_bfloat16* h1gh = (__hip_bfloat16*)alloc((size_t)BT * 128 * 2);
  __hip_bfloat16* h1gl = (__hip_bfloat16*)alloc((size_t)BT * 128 * 2);
  __hip_bfloat16* w2th = (__hip_bfloat16*)alloc((size_t)CC * 64 * 2);
  __hip_bfloat16* w2tl = (__hip_bfloat16*)alloc((size_t)CC * 64 * 2);
  __hip_bfloat16* a2th = (__hip_bfloat16*)alloc((size_t)CC * 64 * 2);
  __hip_bfloat16* a2tl = (__hip_bfloat16*)alloc((size_t)CC * 64 * 2);
  __hip_bfloat16* v2th = (__hip_bfloat16*)alloc((size_t)CC * 64 * 2);
  __hip_bfloat16* v2tl = (__hip_bfloat16*)alloc((size_t)CC * 64 * 2);
  __hip_bfloat16* g2th = (__hip_bfloat16*)alloc((size_t)CC * 128 * 2);
  __hip_bfloat16* g2tl = (__hip_bfloat16*)alloc((size_t)CC * 128 * 2);
  // total ~210 MiB (known-OK envelope: 220 OK, 268 crashed)

  k_prepx<<<16384, 256, 0, stream>>>(hid, shift, xrc, xwc, xkc, xvc, xac, xgc,
                                     xrh, xrl, xw, xkh, xkl, xvh, xvl, xa, xg);
  k_cvt2<<<16384, 256, 0, stream>>>(Wr, Wrh, Wrl);
  k_cvt2<<<16384, 256, 0, stream>>>(Wk, Wkh, Wkl);
  k_cvt2<<<16384, 256, 0, stream>>>(Wv, Wvh, Wvl);
  k_cvt2<<<16384, 256, 0, stream>>>(Wo, Woh, Wol);
  k_tr<<<512, 256, 0, stream>>>(w1, w1t, 64);
  k_tr<<<512, 256, 0, stream>>>(a1, a1t, 64);
  k_tr<<<512, 256, 0, stream>>>(v1, v1t, 32);
  k_tr<<<1024, 256, 0, stream>>>(g1, g1t, 128);
  k_trs<<<512, 256, 0, stream>>>(w2, w2th, w2tl, 64, 6);
  k_trs<<<512, 256, 0, stream>>>(a2, a2th, a2tl, 64, 6);
  k_trs<<<512, 256, 0, stream>>>(v2, v2th, v2tl, 32, 6);   // padded K=64
  k_trs<<<1024, 256, 0, stream>>>(g2, g2th, g2tl, 128, 7);

  k_gemm_bt3<<<dim3(16, 32), 256, 0, stream>>>(xrh, xrl, Wrh, Wrl, rb, BT, CC, CC);
  k_gemm_bt3<<<dim3(16, 32), 256, 0, stream>>>(xkh, xkl, Wkh, Wkl, kb, BT, CC, CC);
  k_gemm_bt3<<<dim3(16, 32), 256, 0, stream>>>(xvh, xvl, Wvh, Wvl, vb, BT, CC, CC);
  k_gemm_bt<<<dim3(16, 1),  256, 0, stream>>>(xw,  w1t, h1w, BT, 64, CC);
  k_gemm_bt<<<dim3(16, 1),  256, 0, stream>>>(xa,  a1t, h1a, BT, 64, CC);
  k_gemm_bt<<<dim3(16, 1),  256, 0, stream>>>(xvh, v1t, h1v, BT, 64, CC);
  k_gemm_bt<<<dim3(16, 2),  256, 0, stream>>>(xg,  g1t, h1g, BT, 128, CC);

  k_act2<<<1024, 256, 0, stream>>>(h1w, h1a, h1v, h1g,
                                   h1wh, h1wl, h1ah, h1al,
                                   h1vh, h1vl, h1gh, h1gl);
  // stage-2 LoRA dots on MFMA (split precision). Overlays now live:
  //   h2w->xw+xa, h2a->xoh+xol, h2v->Wkh+Wkl, h2g->Wrh+Wrl.
  k_gemm_bt3<<<dim3(16, 32), 256, 0, stream>>>(h1wh, h1wl, w2th, w2tl, h2w, BT, CC, 64);
  k_gemm_bt3<<<dim3(16, 32), 256, 0, stream>>>(h1ah, h1al, a2th, a2tl, h2a, BT, CC, 64);
  k_gemm_bt3<<<dim3(16, 32), 256, 0, stream>>>(h1vh, h1vl, v2th, v2tl, h2v, BT, CC, 64);
  k_gemm_bt3<<<dim3(16, 32), 256, 0, stream>>>(h1gh, h1gl, g2th, g2tl, h2g, BT, CC, 128);

  k_gate<<<16384, 256, 0, stream>>>(h2w, h2a, h2v, w0, a0, v0, kkc, kac,
                                    kb, vb, vfirst, rb, rk, db, awb, bwb, bonb);
  k_scan<<<1024, 64, 0, stream>>>(rb, kb, db, awb, bwb, vb, st0, ybuf);
  k_post<<<16384, 256, 0, stream>>>(ybuf, vb, h2g, bonb, gnw, gnb, xoh, xol);
  k_gemm_bt3<<<dim3(16, 32), 256, 0, stream>>>(xoh, xol, Woh, Wol, out, BT, CC, CC);
}

// Round 9
// 1075.714 us; speedup vs baseline: 1.3246x; 1.3246x over previous
//
#include <hip/hip_runtime.h>
#include <hip/hip_bf16.h>

// Problem constants (RWKV-7 Tmix: B=2, T=1024, C=2048, H=32, N=64)
#define BB 2
#define TT 1024
#define CC 2048
#define HH 32
#define BT 2048          // BB*TT tokens
#define GN_EPS 6.4e-4f   // 1e-5 * 8^2

typedef __attribute__((ext_vector_type(8))) __bf16 bf16x8;
typedef __attribute__((ext_vector_type(4))) float f32x4;

__device__ __forceinline__ float sigf(float x) { return 1.0f / (1.0f + expf(-x)); }

__device__ __forceinline__ void split_bf16(float x, __hip_bfloat16& hi, __hip_bfloat16& lo) {
  __hip_bfloat16 h = __float2bfloat16(x);
  hi = h;
  lo = __float2bfloat16(x - __bfloat162float(h));
}

// Sum over each aligned 16-lane group, pure DPP (no LDS pipe on the chain).
__device__ __forceinline__ float red16(float x) {
  x += __int_as_float(__builtin_amdgcn_update_dpp(
      0, __float_as_int(x), 0xB1 /*quad_perm [1,0,3,2]*/, 0xF, 0xF, true));
  x += __int_as_float(__builtin_amdgcn_update_dpp(
      0, __float_as_int(x), 0x4E /*quad_perm [2,3,0,1]*/, 0xF, 0xF, true));
  x += __int_as_float(__builtin_amdgcn_update_dpp(
      0, __float_as_int(x), 0x141 /*row_half_mirror*/, 0xF, 0xF, true));
  x += __int_as_float(__builtin_amdgcn_update_dpp(
      0, __float_as_int(x), 0x140 /*row_mirror*/, 0xF, 0xF, true));
  return x;
}

// ---------------------------------------------------------------------------
// K1: token shift + six lerped projections. r/k/v hi+lo split; w/a/g bf16.
// ---------------------------------------------------------------------------
__global__ __launch_bounds__(256) void k_prepx(
    const float* __restrict__ hid, const float* __restrict__ shift,
    const float* __restrict__ xrc, const float* __restrict__ xwc,
    const float* __restrict__ xkc, const float* __restrict__ xvc,
    const float* __restrict__ xac, const float* __restrict__ xgc,
    __hip_bfloat16* __restrict__ xrh, __hip_bfloat16* __restrict__ xrl,
    __hip_bfloat16* __restrict__ xw,
    __hip_bfloat16* __restrict__ xkh, __hip_bfloat16* __restrict__ xkl,
    __hip_bfloat16* __restrict__ xvh, __hip_bfloat16* __restrict__ xvl,
    __hip_bfloat16* __restrict__ xa, __hip_bfloat16* __restrict__ xg) {
  int idx = blockIdx.x * 256 + threadIdx.x;   // < BT*CC
  int c  = idx & (CC - 1);
  int bt = idx >> 11;
  int t  = bt & (TT - 1);
  int b  = bt >> 10;
  float hcur  = hid[idx];
  float hprev = (t == 0) ? shift[b * CC + c] : hid[idx - CC];
  float xx = hprev - hcur;
  split_bf16(fmaf(xx, xrc[c], hcur), xrh[idx], xrl[idx]);
  split_bf16(fmaf(xx, xkc[c], hcur), xkh[idx], xkl[idx]);
  split_bf16(fmaf(xx, xvc[c], hcur), xvh[idx], xvl[idx]);
  xw[idx] = __float2bfloat16(fmaf(xx, xwc[c], hcur));
  xa[idx] = __float2bfloat16(fmaf(xx, xac[c], hcur));
  xg[idx] = __float2bfloat16(fmaf(xx, xgc[c], hcur));
}

// ---------------------------------------------------------------------------
// K2: f32 -> hi+lo bf16 split (for Wr/Wk/Wv/Wo)
// ---------------------------------------------------------------------------
__global__ __launch_bounds__(256) void k_cvt2(const float* __restrict__ in,
                                              __hip_bfloat16* __restrict__ oh,
                                              __hip_bfloat16* __restrict__ ol) {
  int i = blockIdx.x * 256 + threadIdx.x;
  split_bf16(in[i], oh[i], ol[i]);
}

// ---------------------------------------------------------------------------
// K3: transpose-convert small LoRA "up" weights: in [2048][N0] f32 ->
//     out [NP][2048] bf16 (rows >= N0 zero-padded).  (stage-1 B operands)
// ---------------------------------------------------------------------------
__global__ __launch_bounds__(256) void k_tr(const float* __restrict__ in,
                                            __hip_bfloat16* __restrict__ out,
                                            int N0) {
  int i = blockIdx.x * 256 + threadIdx.x;   // over NP*2048, grid exact
  int n = i >> 11;
  int k = i & 2047;
  float v = (n < N0) ? in[k * N0 + n] : 0.0f;
  out[i] = __float2bfloat16(v);
}

// ---------------------------------------------------------------------------
// K3b: transpose + hi/lo split of stage-2 "down" weights:
//   in [N0][CC] f32 -> out [CC][K0] bf16 hi+lo (K0 = 1<<lgK, rows>=N0 zero).
// ---------------------------------------------------------------------------
__global__ __launch_bounds__(256) void k_trs(const float* __restrict__ in,
                                             __hip_bfloat16* __restrict__ oh,
                                             __hip_bfloat16* __restrict__ ol,
                                             int N0, int lgK) {
  int i = blockIdx.x * 256 + threadIdx.x;   // over CC*K0, grid exact
  int n = i >> lgK;
  int k = i & ((1 << lgK) - 1);
  float v = (k < N0) ? in[k * CC + n] : 0.0f;
  split_bf16(v, oh[i], ol[i]);
}

// ---------------------------------------------------------------------------
// K4: plain bf16 MFMA GEMM, C[M,N] f32 = A[M,K] @ B[N,K]^T  (stage-1 LoRA)
// (round-7 form: direct loads; small grids, not the bottleneck)
// ---------------------------------------------------------------------------
__global__ __launch_bounds__(256) void k_gemm_bt(
    const __hip_bfloat16* __restrict__ A, const __hip_bfloat16* __restrict__ Bm,
    float* __restrict__ Cm, int M, int Nn, int K) {
  int tid  = threadIdx.x;
  int lane = tid & 63;
  int wv   = tid >> 6;
  int l15  = lane & 15;
  int quad = lane >> 4;
  int m0 = blockIdx.x * 128 + wv * 32;
  int n0 = blockIdx.y * 64;
  const __hip_bfloat16* ap0 = A + (size_t)(m0 + l15) * K + quad * 8;
  const __hip_bfloat16* ap1 = ap0 + (size_t)16 * K;
  const __hip_bfloat16* bp  = Bm + (size_t)(n0 + l15) * K + quad * 8;
  f32x4 z = {0.f, 0.f, 0.f, 0.f};
  f32x4 c00 = z, c01 = z, c02 = z, c03 = z;
  f32x4 c10 = z, c11 = z, c12 = z, c13 = z;
  for (int k0 = 0; k0 < K; k0 += 32) {
    bf16x8 a0v = *(const bf16x8*)(ap0 + k0);
    bf16x8 a1v = *(const bf16x8*)(ap1 + k0);
    bf16x8 b0v = *(const bf16x8*)(bp + k0);
    bf16x8 b1v = *(const bf16x8*)(bp + (size_t)16 * K + k0);
    bf16x8 b2v = *(const bf16x8*)(bp + (size_t)32 * K + k0);
    bf16x8 b3v = *(const bf16x8*)(bp + (size_t)48 * K + k0);
    c00 = __builtin_amdgcn_mfma_f32_16x16x32_bf16(a0v, b0v, c00, 0, 0, 0);
    c01 = __builtin_amdgcn_mfma_f32_16x16x32_bf16(a0v, b1v, c01, 0, 0, 0);
    c02 = __builtin_amdgcn_mfma_f32_16x16x32_bf16(a0v, b2v, c02, 0, 0, 0);
    c03 = __builtin_amdgcn_mfma_f32_16x16x32_bf16(a0v, b3v, c03, 0, 0, 0);
    c10 = __builtin_amdgcn_mfma_f32_16x16x32_bf16(a1v, b0v, c10, 0, 0, 0);
    c11 = __builtin_amdgcn_mfma_f32_16x16x32_bf16(a1v, b1v, c11, 0, 0, 0);
    c12 = __builtin_amdgcn_mfma_f32_16x16x32_bf16(a1v, b2v, c12, 0, 0, 0);
    c13 = __builtin_amdgcn_mfma_f32_16x16x32_bf16(a1v, b3v, c13, 0, 0, 0);
  }
  int colb = n0 + l15;
  int row0 = m0 + quad * 4;
#pragma unroll
  for (int r = 0; r < 4; ++r) {
    Cm[(size_t)(row0 + r) * Nn + colb +  0] = c00[r];
    Cm[(size_t)(row0 + r) * Nn + colb + 16] = c01[r];
    Cm[(size_t)(row0 + r) * Nn + colb + 32] = c02[r];
    Cm[(size_t)(row0 + r) * Nn + colb + 48] = c03[r];
    Cm[(size_t)(row0 + 16 + r) * Nn + colb +  0] = c10[r];
    Cm[(size_t)(row0 + 16 + r) * Nn + colb + 16] = c11[r];
    Cm[(size_t)(row0 + 16 + r) * Nn + colb + 32] = c12[r];
    Cm[(size_t)(row0 + 16 + r) * Nn + colb + 48] = c13[r];
  }
}

// ---------------------------------------------------------------------------
// K4b: split-precision GEMM, ROUND-16: m97 LDS-staged structure.
// Register pipelines collapsed 4x (VGPR 64-104; scheduler sinks loads ->
// 289cy serialized L2 latency per load, MfmaUtil 11%). Proven escape =
// global_load_lds staging (scan round-14; m97 GEMM ladder).
// Tile 64x64, BK=32, 4 waves, grid (M/64, N/64): at N=2048 -> 1024 blocks
// = 4 blocks/CU (TLP; a 128^2 tile would give 1/CU - the m102 shape trap).
// Per K-step: stage Ah/Al/Bh/Bl [64][32] bf16 tiles (16 KB) via 4
// global_load_lds(width=16)/wave; __syncthreads (compiler emits vmcnt(0)
// drain - m97-verified); 10 ds_read_b128 frags; 12 MFMA/wave (3 products).
// LDS linear [row][32] == DMA order (lane*16 == (l>>2)*64+(l&3)*16).
// ---------------------------------------------------------------------------
__global__ __launch_bounds__(256, 4) void k_gemm_bt3(
    const __hip_bfloat16* __restrict__ Ah, const __hip_bfloat16* __restrict__ Al,
    const __hip_bfloat16* __restrict__ Bh, const __hip_bfloat16* __restrict__ Bl,
    float* __restrict__ Cm, int M, int Nn, int K) {
  __shared__ __align__(16) __hip_bfloat16 sAh[64 * 32], sAl[64 * 32];
  __shared__ __align__(16) __hip_bfloat16 sBh[64 * 32], sBl[64 * 32];
  int tid  = threadIdx.x;
  int lane = tid & 63;
  int wv   = tid >> 6;
  int l15  = lane & 15;
  int quad = lane >> 4;
  int m0 = blockIdx.x * 64;
  int n0 = blockIdx.y * 64;

  // staging: wave wv fills rows wv*16..+15 of each [64][32] tile.
  // lane l: row = wv*16 + (l>>2), col-group = (l&3)*8. DMA dest is
  // wave-uniform base + lane*16 == linear [row][col] layout (verified).
  int srow = wv * 16 + (lane >> 2);
  int scol = (lane & 3) * 8;
  const __hip_bfloat16* gAh = Ah + (size_t)(m0 + srow) * K + scol;
  const __hip_bfloat16* gAl = Al + (size_t)(m0 + srow) * K + scol;
  const __hip_bfloat16* gBh = Bh + (size_t)(n0 + srow) * K + scol;
  const __hip_bfloat16* gBl = Bl + (size_t)(n0 + srow) * K + scol;
  char* dAh = (char*)sAh + wv * 1024;
  char* dAl = (char*)sAl + wv * 1024;
  char* dBh = (char*)sBh + wv * 1024;
  char* dBl = (char*)sBl + wv * 1024;

  f32x4 z = {0.f, 0.f, 0.f, 0.f};
  f32x4 acc0 = z, acc1 = z, acc2 = z, acc3 = z;

  int aoff = (wv * 16 + l15) * 32 + quad * 8;   // A-frag element offset
  int boff = l15 * 32 + quad * 8;               // B-frag j=0 offset (+512/j)

  for (int k0 = 0; k0 < K; k0 += 32) {
    __builtin_amdgcn_global_load_lds(
        (const __attribute__((address_space(1))) void*)(gAh + k0),
        (__attribute__((address_space(3))) void*)dAh, 16, 0, 0);
    __builtin_amdgcn_global_load_lds(
        (const __attribute__((address_space(1))) void*)(gAl + k0),
        (__attribute__((address_space(3))) void*)dAl, 16, 0, 0);
    __builtin_amdgcn_global_load_lds(
        (const __attribute__((address_space(1))) void*)(gBh + k0),
        (__attribute__((address_space(3))) void*)dBh, 16, 0, 0);
    __builtin_amdgcn_global_load_lds(
        (const __attribute__((address_space(1))) void*)(gBl + k0),
        (__attribute__((address_space(3))) void*)dBl, 16, 0, 0);
    __syncthreads();   // compiler inserts s_waitcnt vmcnt(0) before barrier

    bf16x8 ah = *(const bf16x8*)&sAh[aoff];
    bf16x8 al = *(const bf16x8*)&sAl[aoff];
    bf16x8 bh0 = *(const bf16x8*)&sBh[boff];
    bf16x8 bh1 = *(const bf16x8*)&sBh[boff + 16 * 32];
    bf16x8 bh2 = *(const bf16x8*)&sBh[boff + 32 * 32];
    bf16x8 bh3 = *(const bf16x8*)&sBh[boff + 48 * 32];
    bf16x8 bl0 = *(const bf16x8*)&sBl[boff];
    bf16x8 bl1 = *(const bf16x8*)&sBl[boff + 16 * 32];
    bf16x8 bl2 = *(const bf16x8*)&sBl[boff + 32 * 32];
    bf16x8 bl3 = *(const bf16x8*)&sBl[boff + 48 * 32];

    acc0 = __builtin_amdgcn_mfma_f32_16x16x32_bf16(ah, bh0, acc0, 0, 0, 0);
    acc1 = __builtin_amdgcn_mfma_f32_16x16x32_bf16(ah, bh1, acc1, 0, 0, 0);
    acc2 = __builtin_amdgcn_mfma_f32_16x16x32_bf16(ah, bh2, acc2, 0, 0, 0);
    acc3 = __builtin_amdgcn_mfma_f32_16x16x32_bf16(ah, bh3, acc3, 0, 0, 0);
    acc0 = __builtin_amdgcn_mfma_f32_16x16x32_bf16(ah, bl0, acc0, 0, 0, 0);
    acc1 = __builtin_amdgcn_mfma_f32_16x16x32_bf16(ah, bl1, acc1, 0, 0, 0);
    acc2 = __builtin_amdgcn_mfma_f32_16x16x32_bf16(ah, bl2, acc2, 0, 0, 0);
    acc3 = __builtin_amdgcn_mfma_f32_16x16x32_bf16(ah, bl3, acc3, 0, 0, 0);
    acc0 = __builtin_amdgcn_mfma_f32_16x16x32_bf16(al, bh0, acc0, 0, 0, 0);
    acc1 = __builtin_amdgcn_mfma_f32_16x16x32_bf16(al, bh1, acc1, 0, 0, 0);
    acc2 = __builtin_amdgcn_mfma_f32_16x16x32_bf16(al, bh2, acc2, 0, 0, 0);
    acc3 = __builtin_amdgcn_mfma_f32_16x16x32_bf16(al, bh3, acc3, 0, 0, 0);
    __syncthreads();   // protect LDS reuse by next K-step's DMA
  }

  int row0 = m0 + wv * 16 + quad * 4;
  int colb = n0 + l15;
#pragma unroll
  for (int r = 0; r < 4; ++r) {
    Cm[(size_t)(row0 + r) * Nn + colb +  0] = acc0[r];
    Cm[(size_t)(row0 + r) * Nn + colb + 16] = acc1[r];
    Cm[(size_t)(row0 + r) * Nn + colb + 32] = acc2[r];
    Cm[(size_t)(row0 + r) * Nn + colb + 48] = acc3[r];
  }
}

// ---------------------------------------------------------------------------
// K5: activations + hi/lo split of stage-1 LoRA outputs (MFMA stage-2 prep).
// ---------------------------------------------------------------------------
__global__ __launch_bounds__(256) void k_act2(
    const float* __restrict__ h1w, const float* __restrict__ h1a,
    const float* __restrict__ h1v, const float* __restrict__ h1g,
    __hip_bfloat16* __restrict__ wh, __hip_bfloat16* __restrict__ wl,
    __hip_bfloat16* __restrict__ ah, __hip_bfloat16* __restrict__ al,
    __hip_bfloat16* __restrict__ vh, __hip_bfloat16* __restrict__ vl,
    __hip_bfloat16* __restrict__ gh, __hip_bfloat16* __restrict__ gl) {
  int i = blockIdx.x * 256 + threadIdx.x;   // grid covers BT*128 exactly
  if (i < BT * 64) {
    split_bf16(tanhf(h1w[i]), wh[i], wl[i]);
    split_bf16(h1a[i], ah[i], al[i]);
    split_bf16(h1v[i], vh[i], vl[i]);
  }
  split_bf16(sigf(h1g[i]), gh[i], gl[i]);
}

// ---------------------------------------------------------------------------
// K6: elementwise gates + kk-normalize + per-head bonus. wave == head.
// ---------------------------------------------------------------------------
__global__ __launch_bounds__(256) void k_gate(
    const float* __restrict__ h2w, const float* __restrict__ h2a,
    const float* __restrict__ h2v,
    const float* __restrict__ w0, const float* __restrict__ a0,
    const float* __restrict__ v0, const float* __restrict__ kkc,
    const float* __restrict__ kac, float* __restrict__ kbuf,
    float* __restrict__ vbuf, const float* __restrict__ vfirst,
    const float* __restrict__ rbuf, const float* __restrict__ rk,
    float* __restrict__ dec, float* __restrict__ aw,
    float* __restrict__ bw, float* __restrict__ bonb) {
  int idx = blockIdx.x * 256 + threadIdx.x;   // < BT*CC
  int c = idx & (CC - 1);
  float kv = kbuf[idx], vv = vbuf[idx], vf = vfirst[idx];
  float d_ = 0.60653065971f * sigf(w0[c] + h2w[idx]);   // sigmoid * e^-0.5
  float as = sigf(a0[c] + h2a[idx]);
  float vs = sigf(v0[c] + h2v[idx]);
  float vm = vv + (vf - vv) * vs;
  float kfv = kv * (1.0f + kac[c] * (as - 1.0f));
  float kku = kv * kkc[c];
  float s = kku * kku;     // per-head L2 over 64 lanes (wave == head)
  s += __shfl_xor(s, 1);  s += __shfl_xor(s, 2);  s += __shfl_xor(s, 4);
  s += __shfl_xor(s, 8);  s += __shfl_xor(s, 16); s += __shfl_xor(s, 32);
  float nrm = fmaxf(sqrtf(s), 1e-12f);
  float kkn = kku / nrm;
  float bon = rbuf[idx] * kfv * rk[c];
  bon += __shfl_xor(bon, 1);  bon += __shfl_xor(bon, 2);
  bon += __shfl_xor(bon, 4);  bon += __shfl_xor(bon, 8);
  bon += __shfl_xor(bon, 16); bon += __shfl_xor(bon, 32);
  if ((threadIdx.x & 63) == 0) bonb[(idx >> 11) * HH + (c >> 6)] = bon;
  dec[idx] = d_;
  aw[idx]  = -kkn; bw[idx] = kkn * as;
  kbuf[idx] = kfv; vbuf[idx] = vm;
}

// ---------------------------------------------------------------------------
// K7: WKV7 scan — round-14 LDS-DMA-ring version (passing, 185 µs), unchanged.
// ---------------------------------------------------------------------------
__global__ __launch_bounds__(64, 1) void k_scan(
    const float* __restrict__ rbuf, const float* __restrict__ kf,
    const float* __restrict__ dec, const float* __restrict__ aw,
    const float* __restrict__ bw, const float* __restrict__ vbuf,
    const float* __restrict__ st0, float* __restrict__ ybuf) {
  __shared__ __align__(16) char ldsbuf[16 * 2048];
  int blk = blockIdx.x;                     // 0..1023
  int xcd = blk & 7;
  int q   = blk >> 3;                       // 0..127
  int bh  = xcd * 8 + (q & 7);              // 16 rg-waves of a head share blk%8
  int rg  = q >> 3;                         // 0..15
  int b = bh >> 5, h = bh & 31;
  int lane = threadIdx.x;
  int l15  = lane & 15;
  int row  = rg * 4 + (lane >> 4);
  size_t tokbase = (size_t)b * TT * CC + h * 64;

  f32x4 S = *(const f32x4*)(st0 + ((size_t)bh * 64 + row) * 64 + l15 * 4);
  bool writer = (l15 == 0);
  float* yout = ybuf + tokbase + row;

  // per-lane DMA source pointers (advance +CC per token, all lanes uniform)
  const float* g1 = (lane < 16 ? rbuf : lane < 32 ? kf : lane < 48 ? dec : aw)
                  + tokbase + l15 * 4;
  const float* g2 = (lane < 16) ? (bw + tokbase + l15 * 4)
                                : (vbuf + tokbase + rg * 4);  // lanes>=16: v rows (16 real, rest pad)

  // LDS byte offsets (relative to workgroup LDS base)
  unsigned lbase = (unsigned)(uintptr_t)(__attribute__((address_space(3))) char*)ldsbuf;
  unsigned larr = lbase + (unsigned)(l15 * 16);          // +slot: arrays at 0/256/512/768/1024
  unsigned lvad = lbase + 1280u + (unsigned)((lane >> 4) * 4);  // +slot: v word

#define DMAQ(T)                                                              \
  { char* sb_ = ldsbuf + (((T) & 15) << 11);                                 \
    __builtin_amdgcn_global_load_lds(                                        \
        (const __attribute__((address_space(1))) void*)g1,                   \
        (__attribute__((address_space(3))) void*)sb_, 16, 0, 0);             \
    __builtin_amdgcn_global_load_lds(                                        \
        (const __attribute__((address_space(1))) void*)g2,                   \
        (__attribute__((address_space(3))) void*)(sb_ + 1024), 16, 0, 0);    \
    g1 += CC; g2 += CC; }

#define DSRD(RR, RK, RD, RA, RB, RV, T)                                      \
  { unsigned a_ = larr + (unsigned)(((T) & 15) << 11);                       \
    unsigned v_ = lvad + (unsigned)(((T) & 15) << 11);                       \
    asm volatile("ds_read_b128 %0, %1"             : "=v"(RR) : "v"(a_));    \
    asm volatile("ds_read_b128 %0, %1 offset:256"  : "=v"(RK) : "v"(a_));    \
    asm volatile("ds_read_b128 %0, %1 offset:512"  : "=v"(RD) : "v"(a_));    \
    asm volatile("ds_read_b128 %0, %1 offset:768"  : "=v"(RA) : "v"(a_));    \
    asm volatile("ds_read_b128 %0, %1 offset:1024" : "=v"(RB) : "v"(a_));    \
    asm volatile("ds_read_b32 %0, %1"              : "=v"(RV) : "v"(v_)); }

#define WVM(N) { asm volatile("s_waitcnt vmcnt(" #N ")" ::: "memory");       \
                 __builtin_amdgcn_sched_barrier(0); }
#define WLG    { asm volatile("s_waitcnt lgkmcnt(0)" ::: "memory");          \
                 __builtin_amdgcn_sched_barrier(0); }

#define STEPR(RR, RK, RD, RA, RB, RV, T)                                     \
  { float sa = fmaf(S.w, RA.w, fmaf(S.z, RA.z,                               \
               fmaf(S.y, RA.y, S.x * RA.x)));                                \
    sa = red16(sa);                                                          \
    float vv = RV;                                                           \
    S.x = fmaf(S.x, RD.x, fmaf(sa, RB.x, vv * RK.x));                        \
    S.y = fmaf(S.y, RD.y, fmaf(sa, RB.y, vv * RK.y));                        \
    S.z = fmaf(S.z, RD.z, fmaf(sa, RB.z, vv * RK.z));                        \
    S.w = fmaf(S.w, RD.w, fmaf(sa, RB.w, vv * RK.w));                        \
    float y = fmaf(S.w, RR.w, fmaf(S.z, RR.z,                                \
              fmaf(S.y, RR.y, S.x * RR.x)));                                 \
    y = red16(y);                                                            \
    if (writer) yout[(size_t)(T) * CC] = y; }

  // prologue: DMA tokens 0..15 (32 vmem ops in flight)
  for (int tt = 0; tt < 16; ++tt) DMAQ(tt)

  f32x4 Ar, Ak, Ad, Aa, Ab; float Av;
  f32x4 Br, Bk, Bd, Ba, Bb; float Bv;

  WVM(24)                      // token 0 landed (30 ops after it; 6 slack)
  DSRD(Ar, Ak, Ad, Aa, Ab, Av, 0)
  WLG

  int t = 0;
  // warm-up pairs: t = 0..15 (prologue-issued tokens; exact budget 30+t)
  for (; t < 16; t += 2) {
    DMAQ(t + 16)
    WVM(24)
    DSRD(Br, Bk, Bd, Ba, Bb, Bv, t + 1)
    STEPR(Ar, Ak, Ad, Aa, Ab, Av, t)
    WLG
    DMAQ(t + 17)
    WVM(24)
    DSRD(Ar, Ak, Ad, Aa, Ab, Av, t + 2)
    STEPR(Br, Bk, Bd, Ba, Bb, Bv, t + 1)
    WLG
  }
  // steady pairs: t = 16..1006 (budget 45; 5 slack)
  for (; t < TT - 16; t += 2) {
    DMAQ(t + 16)
    WVM(40)
    DSRD(Br, Bk, Bd, Ba, Bb, Bv, t + 1)
    STEPR(Ar, Ak, Ad, Aa, Ab, Av, t)
    WLG
    DMAQ(t + 17)
    WVM(40)
    DSRD(Ar, Ak, Ad, Aa, Ab, Av, t + 2)
    STEPR(Br, Bk, Bd, Ba, Bb, Bv, t + 1)
    WLG
  }
  // drain, then waitless tail: t = 1008..1023 (all data resident in LDS)
  asm volatile("s_waitcnt vmcnt(0)" ::: "memory");
  __builtin_amdgcn_sched_barrier(0);
  for (; t < TT; t += 2) {
    DSRD(Br, Bk, Bd, Ba, Bb, Bv, t + 1)
    STEPR(Ar, Ak, Ad, Aa, Ab, Av, t)
    WLG
    if (t + 2 < TT) DSRD(Ar, Ak, Ad, Aa, Ab, Av, t + 2)
    STEPR(Br, Bk, Bd, Ba, Bb, Bv, t + 1)
    WLG
  }
#undef DMAQ
#undef DSRD
#undef WVM
#undef WLG
#undef STEPR
}

// ---------------------------------------------------------------------------
// K8: post-scan epilogue: GroupNorm + bonus + g-gate, fully parallel.
// ---------------------------------------------------------------------------
__global__ __launch_bounds__(256) void k_post(
    const float* __restrict__ ybuf, const float* __restrict__ vb,
    const float* __restrict__ gvb, const float* __restrict__ bonb,
    const float* __restrict__ gnw, const float* __restrict__ gnb,
    __hip_bfloat16* __restrict__ xoh, __hip_bfloat16* __restrict__ xol) {
  int tid = threadIdx.x, wv = tid >> 6, lane = tid & 63;
  int id = blockIdx.x * 4 + wv;        // 0..BT*HH-1
  int bt = id >> 5, h = id & 31;
  size_t base = (size_t)bt * CC + h * 64 + lane;
  float y = ybuf[base];
  float s1 = y, s2 = y * y;
#pragma unroll
  for (int off = 1; off < 64; off <<= 1) {
    s1 += __shfl_xor(s1, off);
    s2 += __shfl_xor(s2, off);
  }
  float mean = s1 * (1.0f / 64.0f);
  float var  = s2 * (1.0f / 64.0f) - mean * mean;
  float inv  = rsqrtf(var + GN_EPS);
  float x = fmaf((y - mean) * inv, gnw[h * 64 + lane], gnb[h * 64 + lane])
          + bonb[bt * HH + h] * vb[base];
  split_bf16(x * gvb[base], xoh[base], xol[base]);
}

// ---------------------------------------------------------------------------
extern "C" void kernel_launch(void* const* d_in, const int* in_sizes, int n_in,
                              void* d_out, int out_size, void* d_ws, size_t ws_size,
                              hipStream_t stream) {
  (void)in_sizes; (void)n_in; (void)out_size; (void)ws_size;
  const float* hid    = (const float*)d_in[0];
  const float* shift  = (const float*)d_in[1];
  const float* st0    = (const float*)d_in[2];
  const float* vfirst = (const float*)d_in[3];
  const float* xrc = (const float*)d_in[4];
  const float* xwc = (const float*)d_in[5];
  const float* xkc = (const float*)d_in[6];
  const float* xvc = (const float*)d_in[7];
  const float* xac = (const float*)d_in[8];
  const float* xgc = (const float*)d_in[9];
  const float* w0  = (const float*)d_in[10];
  const float* w1  = (const float*)d_in[11];
  const float* w2  = (const float*)d_in[12];
  const float* a0  = (const float*)d_in[13];
  const float* a1  = (const float*)d_in[14];
  const float* a2  = (const float*)d_in[15];
  const float* v0  = (const float*)d_in[16];
  const float* v1  = (const float*)d_in[17];
  const float* v2  = (const float*)d_in[18];
  const float* g1  = (const float*)d_in[19];
  const float* g2  = (const float*)d_in[20];
  const float* kkc = (const float*)d_in[21];
  const float* kac = (const float*)d_in[22];
  const float* rk  = (const float*)d_in[23];
  const float* Wr  = (const float*)d_in[24];
  const float* Wk  = (const float*)d_in[25];
  const float* Wv  = (const float*)d_in[26];
  const float* Wo  = (const float*)d_in[27];
  const float* gnw = (const float*)d_in[28];
  const float* gnb = (const float*)d_in[29];
  float* out = (float*)d_out;

  char* p = (char*)d_ws;
  auto alloc = [&](size_t n) { char* q = p; p += (n + 255) & ~(size_t)255; return q; };
  const size_t EL = (size_t)BT * CC;

  // --- alias pool: xrh..xvl + Wrh,Wrl dead by k_gate time; db/awb/bwb +
  //     h2g (the old gvb slot) overlay them.
  char* pool = p;
  __hip_bfloat16* xrh = (__hip_bfloat16*)alloc(EL * 2);
  __hip_bfloat16* xrl = (__hip_bfloat16*)alloc(EL * 2);
  __hip_bfloat16* xkh = (__hip_bfloat16*)alloc(EL * 2);
  __hip_bfloat16* xkl = (__hip_bfloat16*)alloc(EL * 2);
  __hip_bfloat16* xvh = (__hip_bfloat16*)alloc(EL * 2);
  __hip_bfloat16* xvl = (__hip_bfloat16*)alloc(EL * 2);
  __hip_bfloat16* Wrh = (__hip_bfloat16*)alloc((size_t)CC * CC * 2);
  __hip_bfloat16* Wrl = (__hip_bfloat16*)alloc((size_t)CC * CC * 2);
  float* db  = (float*)pool;           // overlays xrh+xrl
  float* awb = db + EL;                // overlays xkh+xkl
  float* bwb = db + 2 * EL;            // overlays xvh+xvl
  float* h2g = db + 3 * EL;            // overlays Wrh+Wrl (old gvb slot)

  __hip_bfloat16* Wkh = (__hip_bfloat16*)alloc((size_t)CC * CC * 2);
  __hip_bfloat16* Wkl = (__hip_bfloat16*)alloc((size_t)CC * CC * 2);
  float* ybuf = (float*)Wkh;           // overlays Wkh+Wkl (dead after k-GEMM)
  float* h2v  = (float*)Wkh;           // same region, read by k_gate BEFORE scan writes ybuf

  __hip_bfloat16* Wvh = (__hip_bfloat16*)alloc((size_t)CC * CC * 2);
  __hip_bfloat16* Wvl = (__hip_bfloat16*)alloc((size_t)CC * CC * 2);
  __hip_bfloat16* Woh = (__hip_bfloat16*)alloc((size_t)CC * CC * 2);
  __hip_bfloat16* Wol = (__hip_bfloat16*)alloc((size_t)CC * CC * 2);
  __hip_bfloat16* xw  = (__hip_bfloat16*)alloc(EL * 2);
  __hip_bfloat16* xa  = (__hip_bfloat16*)alloc(EL * 2);
  __hip_bfloat16* xg  = (__hip_bfloat16*)alloc(EL * 2);
  float* h2w = (float*)xw;             // overlays xw+xa (dead after stage-1 GEMMs)
  __hip_bfloat16* w1t = (__hip_bfloat16*)alloc((size_t)64  * CC * 2);
  __hip_bfloat16* a1t = (__hip_bfloat16*)alloc((size_t)64  * CC * 2);
  __hip_bfloat16* v1t = (__hip_bfloat16*)alloc((size_t)64  * CC * 2);
  __hip_bfloat16* g1t = (__hip_bfloat16*)alloc((size_t)128 * CC * 2);
  float* rb  = (float*)alloc(EL * 4);
  float* kb  = (float*)alloc(EL * 4);  // raw k, then k_final in place
  float* vb  = (float*)alloc(EL * 4);  // raw v, then v_mix in place
  float* h1w = (float*)alloc((size_t)BT * 64  * 4);
  float* h1a = (float*)alloc((size_t)BT * 64  * 4);
  float* h1v = (float*)alloc((size_t)BT * 64  * 4);
  float* h1g = (float*)alloc((size_t)BT * 128 * 4);
  __hip_bfloat16* xoh = (__hip_bfloat16*)alloc(EL * 2);
  __hip_bfloat16* xol = (__hip_bfloat16*)alloc(EL * 2);
  float* h2a = (float*)xoh;            // overlays xoh+xol (k_post writes them AFTER k_gate)
  float* bonb = (float*)alloc((size_t)BT * HH * 4);   // per-(token,head) bonus
  // stage-2 split operands (small, fresh):
  __hip_bfloat16* h1wh = (__hip_bfloat16*)alloc((size_t)BT * 64 * 2);
  __hip_bfloat16* h1wl = (__hip_bfloat16*)alloc((size_t)BT * 64 * 2);
  __hip_bfloat16* h1ah = (__hip_bfloat16*)alloc((size_t)BT * 64 * 2);
  __hip_bfloat16* h1al = (__hip_bfloat16*)alloc((size_t)BT * 64 * 2);
  __hip_bfloat16* h1vh = (__hip_bfloat16*)alloc((size_t)BT * 64 * 2);
  __hip_bfloat16* h1vl = (__hip_bfloat16*)alloc((size_t)BT * 64 * 2);
  __hip_bfloat16* h1gh = (__hip_bfloat16*)alloc((size_t)BT * 128 * 2);
  __hip_bfloat16* h1gl = (__hip_bfloat16*)alloc((size_t)BT * 128 * 2);
  __hip_bfloat16* w2th = (__hip_bfloat16*)alloc((size_t)CC * 64 * 2);
  __hip_bfloat16* w2tl = (__hip_bfloat16*)alloc((size_t)CC * 64 * 2);
  __hip_bfloat16* a2th = (__hip_bfloat16*)alloc((size_t)CC * 64 * 2);
  __hip_bfloat16* a2tl = (__hip_bfloat16*)alloc((size_t)CC * 64 * 2);
  __hip_bfloat16* v2th = (__hip_bfloat16*)alloc((size_t)CC * 64 * 2);
  __hip_bfloat16* v2tl = (__hip_bfloat16*)alloc((size_t)CC * 64 * 2);
  __hip_bfloat16* g2th = (__hip_bfloat16*)alloc((size_t)CC * 128 * 2);
  __hip_bfloat16* g2tl = (__hip_bfloat16*)alloc((size_t)CC * 128 * 2);
  // total ~210 MiB (known-OK envelope: 220 OK, 268 crashed)

  k_prepx<<<16384, 256, 0, stream>>>(hid, shift, xrc, xwc, xkc, xvc, xac, xgc,
                                     xrh, xrl, xw, xkh, xkl, xvh, xvl, xa, xg);
  k_cvt2<<<16384, 256, 0, stream>>>(Wr, Wrh, Wrl);
  k_cvt2<<<16384, 256, 0, stream>>>(Wk, Wkh, Wkl);
  k_cvt2<<<16384, 256, 0, stream>>>(Wv, Wvh, Wvl);
  k_cvt2<<<16384, 256, 0, stream>>>(Wo, Woh, Wol);
  k_tr<<<512, 256, 0, stream>>>(w1, w1t, 64);
  k_tr<<<512, 256, 0, stream>>>(a1, a1t, 64);
  k_tr<<<512, 256, 0, stream>>>(v1, v1t, 32);
  k_tr<<<1024, 256, 0, stream>>>(g1, g1t, 128);
  k_trs<<<512, 256, 0, stream>>>(w2, w2th, w2tl, 64, 6);
  k_trs<<<512, 256, 0, stream>>>(a2, a2th, a2tl, 64, 6);
  k_trs<<<512, 256, 0, stream>>>(v2, v2th, v2tl, 32, 6);   // padded K=64
  k_trs<<<1024, 256, 0, stream>>>(g2, g2th, g2tl, 128, 7);

  k_gemm_bt3<<<dim3(32, 32), 256, 0, stream>>>(xrh, xrl, Wrh, Wrl, rb, BT, CC, CC);
  k_gemm_bt3<<<dim3(32, 32), 256, 0, stream>>>(xkh, xkl, Wkh, Wkl, kb, BT, CC, CC);
  k_gemm_bt3<<<dim3(32, 32), 256, 0, stream>>>(xvh, xvl, Wvh, Wvl, vb, BT, CC, CC);
  k_gemm_bt<<<dim3(16, 1),  256, 0, stream>>>(xw,  w1t, h1w, BT, 64, CC);
  k_gemm_bt<<<dim3(16, 1),  256, 0, stream>>>(xa,  a1t, h1a, BT, 64, CC);
  k_gemm_bt<<<dim3(16, 1),  256, 0, stream>>>(xvh, v1t, h1v, BT, 64, CC);
  k_gemm_bt<<<dim3(16, 2),  256, 0, stream>>>(xg,  g1t, h1g, BT, 128, CC);

  k_act2<<<1024, 256, 0, stream>>>(h1w, h1a, h1v, h1g,
                                   h1wh, h1wl, h1ah, h1al,
                                   h1vh, h1vl, h1gh, h1gl);
  // stage-2 LoRA dots on MFMA (split precision). Overlays now live:
  //   h2w->xw+xa, h2a->xoh+xol, h2v->Wkh+Wkl, h2g->Wrh+Wrl.
  k_gemm_bt3<<<dim3(32, 32), 256, 0, stream>>>(h1wh, h1wl, w2th, w2tl, h2w, BT, CC, 64);
  k_gemm_bt3<<<dim3(32, 32), 256, 0, stream>>>(h1ah, h1al, a2th, a2tl, h2a, BT, CC, 64);
  k_gemm_bt3<<<dim3(32, 32), 256, 0, stream>>>(h1vh, h1vl, v2th, v2tl, h2v, BT, CC, 64);
  k_gemm_bt3<<<dim3(32, 32), 256, 0, stream>>>(h1gh, h1gl, g2th, g2tl, h2g, BT, CC, 128);

  k_gate<<<16384, 256, 0, stream>>>(h2w, h2a, h2v, w0, a0, v0, kkc, kac,
                                    kb, vb, vfirst, rb, rk, db, awb, bwb, bonb);
  k_scan<<<1024, 64, 0, stream>>>(rb, kb, db, awb, bwb, vb, st0, ybuf);
  k_post<<<16384, 256, 0, stream>>>(ybuf, vb, h2g, bonb, gnw, gnb, xoh, xol);
  k_gemm_bt3<<<dim3(32, 32), 256, 0, stream>>>(xoh, xol, Woh, Wol, out, BT, CC, CC);
}